// Round 1
// baseline (177.626 us; speedup 1.0000x reference)
//
#include <hip/hip_runtime.h>

#define HH 512
#define WW 512
#define BB 8
#define DXS 0.5f
#define NSTEPS 8

__device__ __forceinline__ void bilinear(const float* __restrict__ c0,
                                         const float* __restrict__ c1,
                                         float px, float py,
                                         float& vx, float& vy) {
    float x = fminf(fmaxf(px, 0.0f), (float)(WW - 1));
    float y = fminf(fmaxf(py, 0.0f), (float)(HH - 1));
    float x0f = floorf(x);
    float y0f = floorf(y);
    int x0 = (int)x0f;
    int y0 = (int)y0f;
    int x1 = min(x0 + 1, WW - 1);
    int y1 = min(y0 + 1, HH - 1);
    float wx = x - x0f;
    float wy = y - y0f;
    float one_wx = 1.0f - wx;
    float one_wy = 1.0f - wy;
    int i00 = y0 * WW + x0;
    int i01 = y0 * WW + x1;
    int i10 = y1 * WW + x0;
    int i11 = y1 * WW + x1;
    float w00 = one_wx * one_wy;
    float w01 = wx * one_wy;
    float w10 = one_wx * wy;
    float w11 = wx * wy;
    vx = c0[i00] * w00 + c0[i01] * w01 + c0[i10] * w10 + c0[i11] * w11;
    vy = c1[i00] * w00 + c1[i01] * w01 + c1[i10] * w10 + c1[i11] * w11;
}

__global__ __launch_bounds__(256) void ivp_loss_kernel(const float* __restrict__ vf_pred,
                                                       const float* __restrict__ vf_true,
                                                       double* __restrict__ acc) {
    int gid = blockIdx.x * 256 + threadIdx.x;
    int b = gid >> 18;                 // / (512*512)
    int pix = gid & (HH * WW - 1);
    int y = pix >> 9;
    int x = pix & (WW - 1);

    const float* t0 = vf_true + (size_t)b * 2 * HH * WW;
    const float* t1 = t0 + HH * WW;
    const float* p0 = vf_pred + (size_t)b * 2 * HH * WW;
    const float* p1 = p0 + HH * WW;

    float ptx = (float)x, pty = (float)y;   // true trajectory state
    float ppx = (float)x, ppy = (float)y;   // pred trajectory state
    float sum = 0.0f;

    for (int s = 0; s < NSTEPS; ++s) {
        float vtx, vty, vpx, vpy;
        bilinear(t0, t1, ptx, pty, vtx, vty);
        bilinear(p0, p1, ppx, ppy, vpx, vpy);
        ptx += DXS * vtx;
        pty += DXS * vty;
        ppx += DXS * vpx;
        ppy += DXS * vpy;
        float dx = ptx - ppx;
        float dy = pty - ppy;
        sum += dx * dx + dy * dy;
    }

    // wave-level reduce (64 lanes)
    for (int off = 32; off > 0; off >>= 1)
        sum += __shfl_down(sum, off, 64);

    __shared__ float wsum[4];
    int lane = threadIdx.x & 63;
    int wave = threadIdx.x >> 6;
    if (lane == 0) wsum[wave] = sum;
    __syncthreads();
    if (threadIdx.x == 0) {
        double blocksum = (double)wsum[0] + (double)wsum[1]
                        + (double)wsum[2] + (double)wsum[3];
        atomicAdd(acc, blocksum);
    }
}

__global__ void ivp_finalize_kernel(const double* __restrict__ acc,
                                    float* __restrict__ out) {
    // mean over (NSTEPS+1) * B * 2 * H * W elements (step 0 contributes 0)
    const double total = (double)(NSTEPS + 1) * BB * 2 * HH * WW;
    out[0] = (float)(acc[0] / total);
}

extern "C" void kernel_launch(void* const* d_in, const int* in_sizes, int n_in,
                              void* d_out, int out_size, void* d_ws, size_t ws_size,
                              hipStream_t stream) {
    const float* vf_pred = (const float*)d_in[0];
    const float* vf_true = (const float*)d_in[1];
    float* out = (float*)d_out;
    double* acc = (double*)d_ws;

    hipMemsetAsync(acc, 0, sizeof(double), stream);

    int total_threads = BB * HH * WW;           // 2,097,152
    int blocks = total_threads / 256;           // 8192
    ivp_loss_kernel<<<blocks, 256, 0, stream>>>(vf_pred, vf_true, acc);
    ivp_finalize_kernel<<<1, 1, 0, stream>>>(acc, out);
}

// Round 2
// 164.974 us; speedup vs baseline: 1.0767x; 1.0767x over previous
//
#include <hip/hip_runtime.h>

#define HH 512
#define WW 512
#define BB 8
#define DXS 0.5f
#define NSTEPS 8

__device__ __forceinline__ void bilinear(const float* __restrict__ c0,
                                         const float* __restrict__ c1,
                                         float px, float py,
                                         float& vx, float& vy) {
    float x = fminf(fmaxf(px, 0.0f), (float)(WW - 1));
    float y = fminf(fmaxf(py, 0.0f), (float)(HH - 1));
    float x0f = floorf(x);
    float y0f = floorf(y);
    int x0 = (int)x0f;
    int y0 = (int)y0f;
    int x1 = min(x0 + 1, WW - 1);
    int y1 = min(y0 + 1, HH - 1);
    float wx = x - x0f;
    float wy = y - y0f;
    float one_wx = 1.0f - wx;
    float one_wy = 1.0f - wy;
    int i00 = y0 * WW + x0;
    int i01 = y0 * WW + x1;
    int i10 = y1 * WW + x0;
    int i11 = y1 * WW + x1;
    float w00 = one_wx * one_wy;
    float w01 = wx * one_wy;
    float w10 = one_wx * wy;
    float w11 = wx * wy;
    vx = c0[i00] * w00 + c0[i01] * w01 + c0[i10] * w10 + c0[i11] * w11;
    vy = c1[i00] * w00 + c1[i01] * w01 + c1[i10] * w10 + c1[i11] * w11;
}

__global__ __launch_bounds__(256) void ivp_loss_kernel(const float* __restrict__ vf_pred,
                                                       const float* __restrict__ vf_true,
                                                       double* __restrict__ acc) {
    // XCD-batch affinity: consecutive blocks round-robin across the 8 XCDs,
    // so batch = blockIdx.x % 8 keeps each batch's 4 MB working set resident
    // in one XCD's 4 MiB L2.
    int b   = blockIdx.x & 7;
    int row = blockIdx.x >> 3;          // 0..511
    int tid = threadIdx.x;

    const float* t0 = vf_true + (size_t)b * 2 * HH * WW;
    const float* t1 = t0 + HH * WW;
    const float* p0 = vf_pred + (size_t)b * 2 * HH * WW;
    const float* p1 = p0 + HH * WW;

    // two pixels per thread: (row, tid) and (row, tid+256) -> 2 independent
    // dependency chains per thread for latency hiding
    float ptx0 = (float)tid,        pty0 = (float)row;
    float ppx0 = ptx0,              ppy0 = pty0;
    float ptx1 = (float)(tid + 256), pty1 = (float)row;
    float ppx1 = ptx1,              ppy1 = pty1;

    float sum = 0.0f;

    #pragma unroll
    for (int s = 0; s < NSTEPS; ++s) {
        float vtx0, vty0, vpx0, vpy0;
        float vtx1, vty1, vpx1, vpy1;
        bilinear(t0, t1, ptx0, pty0, vtx0, vty0);
        bilinear(p0, p1, ppx0, ppy0, vpx0, vpy0);
        bilinear(t0, t1, ptx1, pty1, vtx1, vty1);
        bilinear(p0, p1, ppx1, ppy1, vpx1, vpy1);
        ptx0 += DXS * vtx0;  pty0 += DXS * vty0;
        ppx0 += DXS * vpx0;  ppy0 += DXS * vpy0;
        ptx1 += DXS * vtx1;  pty1 += DXS * vty1;
        ppx1 += DXS * vpx1;  ppy1 += DXS * vpy1;
        float dx0 = ptx0 - ppx0, dy0 = pty0 - ppy0;
        float dx1 = ptx1 - ppx1, dy1 = pty1 - ppy1;
        sum += dx0 * dx0 + dy0 * dy0;
        sum += dx1 * dx1 + dy1 * dy1;
    }

    // wave-level reduce (64 lanes)
    for (int off = 32; off > 0; off >>= 1)
        sum += __shfl_down(sum, off, 64);

    __shared__ float wsum[4];
    int lane = threadIdx.x & 63;
    int wave = threadIdx.x >> 6;
    if (lane == 0) wsum[wave] = sum;
    __syncthreads();
    if (threadIdx.x == 0) {
        double blocksum = (double)wsum[0] + (double)wsum[1]
                        + (double)wsum[2] + (double)wsum[3];
        atomicAdd(acc, blocksum);
    }
}

__global__ void ivp_finalize_kernel(const double* __restrict__ acc,
                                    float* __restrict__ out) {
    const double total = (double)(NSTEPS + 1) * BB * 2 * HH * WW;
    out[0] = (float)(acc[0] / total);
}

extern "C" void kernel_launch(void* const* d_in, const int* in_sizes, int n_in,
                              void* d_out, int out_size, void* d_ws, size_t ws_size,
                              hipStream_t stream) {
    const float* vf_pred = (const float*)d_in[0];
    const float* vf_true = (const float*)d_in[1];
    float* out = (float*)d_out;
    double* acc = (double*)d_ws;

    hipMemsetAsync(acc, 0, sizeof(double), stream);

    int blocks = BB * HH;                      // 4096 blocks, 2 px/thread
    ivp_loss_kernel<<<blocks, 256, 0, stream>>>(vf_pred, vf_true, acc);
    ivp_finalize_kernel<<<1, 1, 0, stream>>>(acc, out);
}

// Round 3
// 85.892 us; speedup vs baseline: 2.0680x; 1.9207x over previous
//
#include <hip/hip_runtime.h>

#define HH 512
#define WW 512
#define BB 8
#define HW (HH * WW)
#define DXS 0.5f
#define NSTEPS 8

// ---------------- packed-layout path ----------------

// pack (B,2,H,W) -> (B,H,W,2) for both fields
__global__ __launch_bounds__(256) void pack_kernel(const float* __restrict__ vf_true,
                                                   const float* __restrict__ vf_pred,
                                                   float2* __restrict__ tpack,
                                                   float2* __restrict__ ppack) {
    int gid = blockIdx.x * 256 + threadIdx.x;      // over B*H*W
    int b   = gid >> 18;
    int pix = gid & (HW - 1);
    const float* t = vf_true + (size_t)b * 2 * HW;
    const float* p = vf_pred + (size_t)b * 2 * HW;
    tpack[gid] = make_float2(t[pix], t[pix + HW]);
    ppack[gid] = make_float2(p[pix], p[pix + HW]);
}

__device__ __forceinline__ void bilin2(const float2* __restrict__ f,
                                       float px, float py,
                                       float& vx, float& vy) {
    float x = fminf(fmaxf(px, 0.0f), (float)(WW - 1));
    float y = fminf(fmaxf(py, 0.0f), (float)(HH - 1));
    // clamp corner to 510 and let wx run to 1.0: identical to ref semantics,
    // guarantees x1=x0+1 and y1=y0+1 are in-bounds (no special cases)
    float x0f = fminf(floorf(x), (float)(WW - 2));
    float y0f = fminf(floorf(y), (float)(HH - 2));
    int x0 = (int)x0f;
    int y0 = (int)y0f;
    float wx = x - x0f;
    float wy = y - y0f;
    const float2* r0 = f + y0 * WW + x0;
    const float2* r1 = r0 + WW;
    float2 v00 = r0[0];
    float2 v01 = r0[1];
    float2 v10 = r1[0];
    float2 v11 = r1[1];
    float w00 = (1.0f - wx) * (1.0f - wy);
    float w01 = wx * (1.0f - wy);
    float w10 = (1.0f - wx) * wy;
    float w11 = wx * wy;
    vx = v00.x * w00 + v01.x * w01 + v10.x * w10 + v11.x * w11;
    vy = v00.y * w00 + v01.y * w01 + v10.y * w10 + v11.y * w11;
}

__global__ __launch_bounds__(256) void ivp_loss_packed(const float2* __restrict__ tpack,
                                                       const float2* __restrict__ ppack,
                                                       double* __restrict__ acc) {
    // XCD-batch affinity: blockIdx % 8 == XCD id == batch
    int b   = blockIdx.x & 7;
    int row = blockIdx.x >> 3;          // 0..511
    int tid = threadIdx.x;

    const float2* t = tpack + (size_t)b * HW;
    const float2* p = ppack + (size_t)b * HW;

    float ptx0 = (float)tid,         pty0 = (float)row;
    float ppx0 = ptx0,               ppy0 = pty0;
    float ptx1 = (float)(tid + 256), pty1 = (float)row;
    float ppx1 = ptx1,               ppy1 = pty1;

    float sum = 0.0f;

    #pragma unroll
    for (int s = 0; s < NSTEPS; ++s) {
        float vtx0, vty0, vpx0, vpy0;
        float vtx1, vty1, vpx1, vpy1;
        bilin2(t, ptx0, pty0, vtx0, vty0);
        bilin2(p, ppx0, ppy0, vpx0, vpy0);
        bilin2(t, ptx1, pty1, vtx1, vty1);
        bilin2(p, ppx1, ppy1, vpx1, vpy1);
        ptx0 += DXS * vtx0;  pty0 += DXS * vty0;
        ppx0 += DXS * vpx0;  ppy0 += DXS * vpy0;
        ptx1 += DXS * vtx1;  pty1 += DXS * vty1;
        ppx1 += DXS * vpx1;  ppy1 += DXS * vpy1;
        float dx0 = ptx0 - ppx0, dy0 = pty0 - ppy0;
        float dx1 = ptx1 - ppx1, dy1 = pty1 - ppy1;
        sum += dx0 * dx0 + dy0 * dy0;
        sum += dx1 * dx1 + dy1 * dy1;
    }

    for (int off = 32; off > 0; off >>= 1)
        sum += __shfl_down(sum, off, 64);

    __shared__ float wsum[4];
    int lane = threadIdx.x & 63;
    int wave = threadIdx.x >> 6;
    if (lane == 0) wsum[wave] = sum;
    __syncthreads();
    if (threadIdx.x == 0) {
        double blocksum = (double)wsum[0] + (double)wsum[1]
                        + (double)wsum[2] + (double)wsum[3];
        atomicAdd(acc, blocksum);
    }
}

// ---------------- fallback path (unpacked, from R2) ----------------

__device__ __forceinline__ void bilinear(const float* __restrict__ c0,
                                         const float* __restrict__ c1,
                                         float px, float py,
                                         float& vx, float& vy) {
    float x = fminf(fmaxf(px, 0.0f), (float)(WW - 1));
    float y = fminf(fmaxf(py, 0.0f), (float)(HH - 1));
    float x0f = fminf(floorf(x), (float)(WW - 2));
    float y0f = fminf(floorf(y), (float)(HH - 2));
    int x0 = (int)x0f;
    int y0 = (int)y0f;
    float wx = x - x0f;
    float wy = y - y0f;
    int i00 = y0 * WW + x0;
    float w00 = (1.0f - wx) * (1.0f - wy);
    float w01 = wx * (1.0f - wy);
    float w10 = (1.0f - wx) * wy;
    float w11 = wx * wy;
    vx = c0[i00] * w00 + c0[i00 + 1] * w01 + c0[i00 + WW] * w10 + c0[i00 + WW + 1] * w11;
    vy = c1[i00] * w00 + c1[i00 + 1] * w01 + c1[i00 + WW] * w10 + c1[i00 + WW + 1] * w11;
}

__global__ __launch_bounds__(256) void ivp_loss_kernel(const float* __restrict__ vf_pred,
                                                       const float* __restrict__ vf_true,
                                                       double* __restrict__ acc) {
    int b   = blockIdx.x & 7;
    int row = blockIdx.x >> 3;
    int tid = threadIdx.x;

    const float* t0 = vf_true + (size_t)b * 2 * HW;
    const float* t1 = t0 + HW;
    const float* p0 = vf_pred + (size_t)b * 2 * HW;
    const float* p1 = p0 + HW;

    float ptx0 = (float)tid,         pty0 = (float)row;
    float ppx0 = ptx0,               ppy0 = pty0;
    float ptx1 = (float)(tid + 256), pty1 = (float)row;
    float ppx1 = ptx1,               ppy1 = pty1;

    float sum = 0.0f;

    #pragma unroll
    for (int s = 0; s < NSTEPS; ++s) {
        float vtx0, vty0, vpx0, vpy0;
        float vtx1, vty1, vpx1, vpy1;
        bilinear(t0, t1, ptx0, pty0, vtx0, vty0);
        bilinear(p0, p1, ppx0, ppy0, vpx0, vpy0);
        bilinear(t0, t1, ptx1, pty1, vtx1, vty1);
        bilinear(p0, p1, ppx1, ppy1, vpx1, vpy1);
        ptx0 += DXS * vtx0;  pty0 += DXS * vty0;
        ppx0 += DXS * vpx0;  ppy0 += DXS * vpy0;
        ptx1 += DXS * vtx1;  pty1 += DXS * vty1;
        ppx1 += DXS * vpx1;  ppy1 += DXS * vpy1;
        float dx0 = ptx0 - ppx0, dy0 = pty0 - ppy0;
        float dx1 = ptx1 - ppx1, dy1 = pty1 - ppy1;
        sum += dx0 * dx0 + dy0 * dy0;
        sum += dx1 * dx1 + dy1 * dy1;
    }

    for (int off = 32; off > 0; off >>= 1)
        sum += __shfl_down(sum, off, 64);

    __shared__ float wsum[4];
    int lane = threadIdx.x & 63;
    int wave = threadIdx.x >> 6;
    if (lane == 0) wsum[wave] = sum;
    __syncthreads();
    if (threadIdx.x == 0) {
        double blocksum = (double)wsum[0] + (double)wsum[1]
                        + (double)wsum[2] + (double)wsum[3];
        atomicAdd(acc, blocksum);
    }
}

// ---------------- finalize ----------------

__global__ void ivp_finalize_kernel(const double* __restrict__ acc,
                                    float* __restrict__ out) {
    const double total = (double)(NSTEPS + 1) * BB * 2 * HW;
    out[0] = (float)(acc[0] / total);
}

extern "C" void kernel_launch(void* const* d_in, const int* in_sizes, int n_in,
                              void* d_out, int out_size, void* d_ws, size_t ws_size,
                              hipStream_t stream) {
    const float* vf_pred = (const float*)d_in[0];
    const float* vf_true = (const float*)d_in[1];
    float* out = (float*)d_out;

    const size_t pack_bytes = (size_t)BB * HW * 2 * sizeof(float);  // 16 MB per field
    const size_t need = 256 + 2 * pack_bytes;

    double* acc = (double*)d_ws;
    hipMemsetAsync(acc, 0, sizeof(double), stream);

    if (ws_size >= need) {
        float2* tpack = (float2*)((char*)d_ws + 256);
        float2* ppack = (float2*)((char*)d_ws + 256 + pack_bytes);
        pack_kernel<<<BB * HW / 256, 256, 0, stream>>>(vf_true, vf_pred, tpack, ppack);
        ivp_loss_packed<<<BB * HH, 256, 0, stream>>>(tpack, ppack, acc);
    } else {
        ivp_loss_kernel<<<BB * HH, 256, 0, stream>>>(vf_pred, vf_true, acc);
    }
    ivp_finalize_kernel<<<1, 1, 0, stream>>>(acc, out);
}

// Round 4
// 84.272 us; speedup vs baseline: 2.1078x; 1.0192x over previous
//
#include <hip/hip_runtime.h>

#define HH 512
#define WW 512
#define BB 8
#define HW (HH * WW)
#define DXS 0.5f
#define NSTEPS 8

// 16B vector with 8B alignment guarantee (corner-pair loads are only 8B-aligned)
typedef float f4u __attribute__((ext_vector_type(4), aligned(8)));
typedef float f4a __attribute__((ext_vector_type(4)));  // 16B-aligned variant

// ---------------- pack prepass ----------------
// (B,2,H,W) -> (B,H,W,2), with XCD-batch affinity (blk%8 == batch) so batch b's
// packed lines land (and stay) in XCD b's L2 for the main kernel to re-read.
__global__ __launch_bounds__(256) void pack_kernel(const float* __restrict__ vf_true,
                                                   const float* __restrict__ vf_pred,
                                                   float2* __restrict__ tpack,
                                                   float2* __restrict__ ppack) {
    int b     = blockIdx.x & 7;
    int chunk = blockIdx.x >> 3;                  // 0..255
    int i     = chunk * 256 + threadIdx.x;        // pixel-group within batch
    int pix   = i * 4;

    const float* t = vf_true + (size_t)b * 2 * HW;
    const float* p = vf_pred + (size_t)b * 2 * HW;

    f4a tx = *(const f4a*)(t + pix);
    f4a ty = *(const f4a*)(t + pix + HW);
    f4a px = *(const f4a*)(p + pix);
    f4a py = *(const f4a*)(p + pix + HW);

    f4a* ot = (f4a*)(tpack + (size_t)b * HW + pix);
    f4a* op = (f4a*)(ppack + (size_t)b * HW + pix);
    ot[0] = (f4a){tx.x, ty.x, tx.y, ty.y};
    ot[1] = (f4a){tx.z, ty.z, tx.w, ty.w};
    op[0] = (f4a){px.x, py.x, px.y, py.y};
    op[1] = (f4a){px.z, py.z, px.w, py.w};
}

// ---------------- bilinear: 2 x dwordx4 per sample ----------------
__device__ __forceinline__ void bilin4(const float2* __restrict__ f,
                                       float px, float py,
                                       float& vx, float& vy) {
    float x = fminf(fmaxf(px, 0.0f), (float)(WW - 1));
    float y = fminf(fmaxf(py, 0.0f), (float)(HH - 1));
    float x0f = fminf(floorf(x), (float)(WW - 2));
    float y0f = fminf(floorf(y), (float)(HH - 2));
    float wx = x - x0f;
    float wy = y - y0f;
    int idx = (int)fmaf(y0f, (float)WW, x0f);     // exact: < 2^24
    const f4u* r0 = (const f4u*)(f + idx);
    const f4u* r1 = (const f4u*)(f + idx + WW);
    f4u a = *r0;   // v00.x v00.y v01.x v01.y
    f4u c = *r1;   // v10.x v10.y v11.x v11.y
    float ax = a.x + wx * (a.z - a.x);
    float ay = a.y + wx * (a.w - a.y);
    float cx = c.x + wx * (c.z - c.x);
    float cy = c.y + wx * (c.w - c.y);
    vx = ax + wy * (cx - ax);
    vy = ay + wy * (cy - ay);
}

__global__ __launch_bounds__(256) void ivp_loss_packed(const float2* __restrict__ tpack,
                                                       const float2* __restrict__ ppack,
                                                       double* __restrict__ acc) {
    int b   = blockIdx.x & 7;          // XCD-batch affinity
    int row = blockIdx.x >> 3;         // 0..511
    int tid = threadIdx.x;

    const float2* t = tpack + (size_t)b * HW;
    const float2* p = ppack + (size_t)b * HW;

    float ptx0 = (float)tid,         pty0 = (float)row;
    float ppx0 = ptx0,               ppy0 = pty0;
    float ptx1 = (float)(tid + 256), pty1 = (float)row;
    float ppx1 = ptx1,               ppy1 = pty1;

    float sum = 0.0f;

    #pragma unroll
    for (int s = 0; s < NSTEPS; ++s) {
        float vtx0, vty0, vpx0, vpy0;
        float vtx1, vty1, vpx1, vpy1;
        bilin4(t, ptx0, pty0, vtx0, vty0);
        bilin4(p, ppx0, ppy0, vpx0, vpy0);
        bilin4(t, ptx1, pty1, vtx1, vty1);
        bilin4(p, ppx1, ppy1, vpx1, vpy1);
        ptx0 += DXS * vtx0;  pty0 += DXS * vty0;
        ppx0 += DXS * vpx0;  ppy0 += DXS * vpy0;
        ptx1 += DXS * vtx1;  pty1 += DXS * vty1;
        ppx1 += DXS * vpx1;  ppy1 += DXS * vpy1;
        float dx0 = ptx0 - ppx0, dy0 = pty0 - ppy0;
        float dx1 = ptx1 - ppx1, dy1 = pty1 - ppy1;
        sum += dx0 * dx0 + dy0 * dy0;
        sum += dx1 * dx1 + dy1 * dy1;
    }

    for (int off = 32; off > 0; off >>= 1)
        sum += __shfl_down(sum, off, 64);

    __shared__ float wsum[4];
    int lane = threadIdx.x & 63;
    int wave = threadIdx.x >> 6;
    if (lane == 0) wsum[wave] = sum;
    __syncthreads();
    if (threadIdx.x == 0) {
        double blocksum = (double)wsum[0] + (double)wsum[1]
                        + (double)wsum[2] + (double)wsum[3];
        atomicAdd(acc, blocksum);
    }
}

// ---------------- fallback path (no workspace): unpacked float2-free ----------------
__device__ __forceinline__ void bilinear(const float* __restrict__ c0,
                                         const float* __restrict__ c1,
                                         float px, float py,
                                         float& vx, float& vy) {
    float x = fminf(fmaxf(px, 0.0f), (float)(WW - 1));
    float y = fminf(fmaxf(py, 0.0f), (float)(HH - 1));
    float x0f = fminf(floorf(x), (float)(WW - 2));
    float y0f = fminf(floorf(y), (float)(HH - 2));
    float wx = x - x0f;
    float wy = y - y0f;
    int i00 = (int)fmaf(y0f, (float)WW, x0f);
    float w00 = (1.0f - wx) * (1.0f - wy);
    float w01 = wx * (1.0f - wy);
    float w10 = (1.0f - wx) * wy;
    float w11 = wx * wy;
    vx = c0[i00] * w00 + c0[i00 + 1] * w01 + c0[i00 + WW] * w10 + c0[i00 + WW + 1] * w11;
    vy = c1[i00] * w00 + c1[i00 + 1] * w01 + c1[i00 + WW] * w10 + c1[i00 + WW + 1] * w11;
}

__global__ __launch_bounds__(256) void ivp_loss_kernel(const float* __restrict__ vf_pred,
                                                       const float* __restrict__ vf_true,
                                                       double* __restrict__ acc) {
    int b   = blockIdx.x & 7;
    int row = blockIdx.x >> 3;
    int tid = threadIdx.x;

    const float* t0 = vf_true + (size_t)b * 2 * HW;
    const float* t1 = t0 + HW;
    const float* p0 = vf_pred + (size_t)b * 2 * HW;
    const float* p1 = p0 + HW;

    float ptx0 = (float)tid,         pty0 = (float)row;
    float ppx0 = ptx0,               ppy0 = pty0;
    float ptx1 = (float)(tid + 256), pty1 = (float)row;
    float ppx1 = ptx1,               ppy1 = pty1;

    float sum = 0.0f;

    #pragma unroll
    for (int s = 0; s < NSTEPS; ++s) {
        float vtx0, vty0, vpx0, vpy0;
        float vtx1, vty1, vpx1, vpy1;
        bilinear(t0, t1, ptx0, pty0, vtx0, vty0);
        bilinear(p0, p1, ppx0, ppy0, vpx0, vpy0);
        bilinear(t0, t1, ptx1, pty1, vtx1, vty1);
        bilinear(p0, p1, ppx1, ppy1, vpx1, vpy1);
        ptx0 += DXS * vtx0;  pty0 += DXS * vty0;
        ppx0 += DXS * vpx0;  ppy0 += DXS * vpy0;
        ptx1 += DXS * vtx1;  pty1 += DXS * vty1;
        ppx1 += DXS * vpx1;  ppy1 += DXS * vpy1;
        float dx0 = ptx0 - ppx0, dy0 = pty0 - ppy0;
        float dx1 = ptx1 - ppx1, dy1 = pty1 - ppy1;
        sum += dx0 * dx0 + dy0 * dy0;
        sum += dx1 * dx1 + dy1 * dy1;
    }

    for (int off = 32; off > 0; off >>= 1)
        sum += __shfl_down(sum, off, 64);

    __shared__ float wsum[4];
    int lane = threadIdx.x & 63;
    int wave = threadIdx.x >> 6;
    if (lane == 0) wsum[wave] = sum;
    __syncthreads();
    if (threadIdx.x == 0) {
        double blocksum = (double)wsum[0] + (double)wsum[1]
                        + (double)wsum[2] + (double)wsum[3];
        atomicAdd(acc, blocksum);
    }
}

// ---------------- finalize ----------------
__global__ void ivp_finalize_kernel(const double* __restrict__ acc,
                                    float* __restrict__ out) {
    const double total = (double)(NSTEPS + 1) * BB * 2 * HW;
    out[0] = (float)(acc[0] / total);
}

extern "C" void kernel_launch(void* const* d_in, const int* in_sizes, int n_in,
                              void* d_out, int out_size, void* d_ws, size_t ws_size,
                              hipStream_t stream) {
    const float* vf_pred = (const float*)d_in[0];
    const float* vf_true = (const float*)d_in[1];
    float* out = (float*)d_out;

    const size_t pack_bytes = (size_t)BB * HW * 2 * sizeof(float);  // 16 MB per field
    const size_t need = 256 + 2 * pack_bytes;

    double* acc = (double*)d_ws;
    hipMemsetAsync(acc, 0, sizeof(double), stream);

    if (ws_size >= need) {
        float2* tpack = (float2*)((char*)d_ws + 256);
        float2* ppack = (float2*)((char*)d_ws + 256 + pack_bytes);
        pack_kernel<<<BB * HW / 4 / 256, 256, 0, stream>>>(vf_true, vf_pred, tpack, ppack);
        ivp_loss_packed<<<BB * HH, 256, 0, stream>>>(tpack, ppack, acc);
    } else {
        ivp_loss_kernel<<<BB * HH, 256, 0, stream>>>(vf_pred, vf_true, acc);
    }
    ivp_finalize_kernel<<<1, 1, 0, stream>>>(acc, out);
}